// Round 6
// baseline (2760.783 us; speedup 1.0000x reference)
//
#include <hip/hip_runtime.h>

#define N_ROWS   16384
#define DIM      64
#define K_CODES  8192
#define EMAX     (1.0f / 8192.0f)
#define NSPLIT   16
#define CPS      (K_CODES / NSPLIT)          // 512 codes per slice
#define SCAN_BLOCKS 1024                      // 4096 waves: 256 rowgrps x 16 splits
#define EPI_BLOCKS  (N_ROWS / 64)            // 256
#define EPI_THREADS 512
#define MAXCAND  16

typedef __attribute__((ext_vector_type(8))) short bf16x8;
typedef __attribute__((ext_vector_type(4))) float f32x4;

// ---- ws layout ----
// [0, 2MB)      : zbf   ushort[N_ROWS*64]
// [2MB, 3MB)    : cbbf  ushort[K_CODES*64]
// [3MB, +64KB)  : zn    float[N_ROWS]
// +64KB         : wr    float[N_ROWS]
// +128KB        : rowcnt uint[N_ROWS]
// +192KB        : bidx  int[N_ROWS]
// +256KB        : lred  float[EPI_BLOCKS]
#define WS_ZBF(ws)  ((unsigned short*)(ws))
#define WS_CBBF(ws) ((unsigned short*)((char*)(ws) + (2u<<20)))
#define WS_ZN(ws)   ((float*)((char*)(ws) + (3u<<20)))
#define WS_WR(ws)   ((float*)((char*)(ws) + (3u<<20) + (64u<<10)))
#define WS_CNT(ws)  ((unsigned*)((char*)(ws) + (3u<<20) + (128u<<10)))
#define WS_BIDX(ws) ((int*)((char*)(ws) + (3u<<20) + (192u<<10)))
#define WS_LRED(ws) ((float*)((char*)(ws) + (3u<<20) + (256u<<10)))
// scratch hosted in d_out (fully rewritten before use each call; epilogue
// later overwrites every out element):
//   smax float[NSPLIT][N_ROWS] at out+0 (1MB); cand ushort[N_ROWS][16] at out+1MB
#define OUT_SMAX(out) ((float*)(out))
#define OUT_CAND(out) ((unsigned short*)((char*)(out) + (1u<<20)))

__device__ __forceinline__ unsigned short f2bf_rn(float x) {
    unsigned u = __float_as_uint(x);
    return (unsigned short)((u + 0x7FFFu + ((u >> 16) & 1u)) >> 16);
}
__device__ __forceinline__ bf16x8 ldbf8(const unsigned short* p) {
    uint4 t = *(const uint4*)p;
    return *(bf16x8*)&t;
}

// ---- prep: zn (exact chain), window, bf16(z), zero counters ----
__global__ __launch_bounds__(256)
void vq_prep_kernel(const float* __restrict__ z, float* __restrict__ zn_o,
                    float* __restrict__ wr_o, unsigned short* __restrict__ zbf,
                    unsigned* __restrict__ rowcnt)
{
    const int row = blockIdx.x * 256 + threadIdx.x;
    float zs[DIM];
    #pragma unroll
    for (int ch = 0; ch < 16; ++ch) {
        float4 v = *(const float4*)(z + (size_t)row * DIM + ch * 4);
        zs[4*ch+0] = v.x; zs[4*ch+1] = v.y; zs[4*ch+2] = v.z; zs[4*ch+3] = v.w;
    }
    float r8[8];
    #pragma unroll
    for (int j = 0; j < 8; ++j) r8[j] = __fmul_rn(zs[j], zs[j]);
    #pragma unroll
    for (int i = 8; i < DIM; i += 8)
        #pragma unroll
        for (int j = 0; j < 8; ++j)
            r8[j] = __fadd_rn(r8[j], __fmul_rn(zs[i+j], zs[i+j]));
    float zn = __fadd_rn(__fadd_rn(__fadd_rn(r8[0], r8[1]), __fadd_rn(r8[2], r8[3])),
                         __fadd_rn(__fadd_rn(r8[4], r8[5]), __fadd_rn(r8[6], r8[7])));
    float S = 0.0f;
    #pragma unroll
    for (int k = 0; k < DIM; ++k) S += fabsf(zs[k]);

    zn_o[row] = zn;
    wr_o[row] = 0x1p-6f * EMAX * S * 1.02f + 2e-5f;
    rowcnt[row] = 0u;

    #pragma unroll
    for (int g = 0; g < 8; ++g) {
        uint4 o;
        o.x = (unsigned)f2bf_rn(zs[8*g+0]) | ((unsigned)f2bf_rn(zs[8*g+1]) << 16);
        o.y = (unsigned)f2bf_rn(zs[8*g+2]) | ((unsigned)f2bf_rn(zs[8*g+3]) << 16);
        o.z = (unsigned)f2bf_rn(zs[8*g+4]) | ((unsigned)f2bf_rn(zs[8*g+5]) << 16);
        o.w = (unsigned)f2bf_rn(zs[8*g+6]) | ((unsigned)f2bf_rn(zs[8*g+7]) << 16);
        *(uint4*)(zbf + (size_t)row * DIM + g * 8) = o;
    }
}

__global__ __launch_bounds__(256)
void vq_cbconv_kernel(const float* __restrict__ cb, unsigned short* __restrict__ cbbf)
{
    const int code = blockIdx.x * 256 + threadIdx.x;
    #pragma unroll
    for (int g = 0; g < 8; ++g) {
        float4 a = *(const float4*)(cb + (size_t)code * DIM + g * 8);
        float4 b = *(const float4*)(cb + (size_t)code * DIM + g * 8 + 4);
        uint4 o;
        o.x = (unsigned)f2bf_rn(a.x) | ((unsigned)f2bf_rn(a.y) << 16);
        o.y = (unsigned)f2bf_rn(a.z) | ((unsigned)f2bf_rn(a.w) << 16);
        o.z = (unsigned)f2bf_rn(b.x) | ((unsigned)f2bf_rn(b.y) << 16);
        o.w = (unsigned)f2bf_rn(b.z) | ((unsigned)f2bf_rn(b.w) << 16);
        *(uint4*)(cbbf + (size_t)code * DIM + g * 8) = o;
    }
}

// ---- common wave setup for scans: B frags (z rows) in regs ----
#define SCAN_PROLOGUE()                                                        \
    const int lane = threadIdx.x & 63;                                         \
    const int gw   = blockIdx.x * 4 + (threadIdx.x >> 6);                      \
    const int rowgrp = gw >> 4;                                                \
    const int split  = gw & (NSPLIT - 1);                                      \
    const int code_base = split * CPS;                                         \
    const int l15 = lane & 15, lc = lane >> 4;                                 \
    bf16x8 bfrag[4][2];                                                        \
    int rowv[4];                                                               \
    _Pragma("unroll")                                                          \
    for (int nt = 0; nt < 4; ++nt) {                                           \
        int row = rowgrp * 64 + nt * 16 + l15;                                 \
        rowv[nt] = row;                                                        \
        const unsigned short* p = zbf + (size_t)row * DIM + lc * 8;            \
        bfrag[nt][0] = ldbf8(p);                                               \
        bfrag[nt][1] = ldbf8(p + 32);                                          \
    }                                                                          \
    _Pragma("unroll")                                                          \
    for (int nt = 0; nt < 4; ++nt) {                                           \
        uint4& u0 = *(uint4*)&bfrag[nt][0];                                    \
        asm volatile("" : "+v"(u0.x), "+v"(u0.y), "+v"(u0.z), "+v"(u0.w));     \
        uint4& u1 = *(uint4*)&bfrag[nt][1];                                    \
        asm volatile("" : "+v"(u1.x), "+v"(u1.y), "+v"(u1.z), "+v"(u1.w));     \
    }

// ---- scan A: per-(row, slice) max of bf16 dot ----
__global__ __launch_bounds__(256, 4)
void vq_scanmax_kernel(const unsigned short* __restrict__ zbf,
                       const unsigned short* __restrict__ cbbf,
                       float* __restrict__ smax)
{
    SCAN_PROLOGUE();
    float vmax[4];
    #pragma unroll
    for (int nt = 0; nt < 4; ++nt) vmax[nt] = -1e30f;

    #pragma unroll 1
    for (int ct = 0; ct < CPS / 16; ++ct) {
        const unsigned short* ap = cbbf + (size_t)(code_base + ct * 16 + l15) * DIM + lc * 8;
        bf16x8 a0 = ldbf8(ap), a1 = ldbf8(ap + 32);
        #pragma unroll
        for (int nt = 0; nt < 4; ++nt) {
            f32x4 acc = {0.f, 0.f, 0.f, 0.f};
            acc = __builtin_amdgcn_mfma_f32_16x16x32_bf16(a0, bfrag[nt][0], acc, 0, 0, 0);
            acc = __builtin_amdgcn_mfma_f32_16x16x32_bf16(a1, bfrag[nt][1], acc, 0, 0, 0);
            vmax[nt] = fmaxf(vmax[nt],
                             fmaxf(fmaxf(acc[0], acc[1]), fmaxf(acc[2], acc[3])));
        }
    }
    #pragma unroll
    for (int nt = 0; nt < 4; ++nt) {
        float v = vmax[nt];
        v = fmaxf(v, __shfl_xor(v, 16));
        v = fmaxf(v, __shfl_xor(v, 32));
        if (lc == 0) smax[(size_t)split * N_ROWS + rowv[nt]] = v;   // coalesced 64B
    }
}

// ---- scan B: filter vs global-row threshold, append candidate codes ----
__global__ __launch_bounds__(256, 4)
void vq_scanfilter_kernel(const unsigned short* __restrict__ zbf,
                          const unsigned short* __restrict__ cbbf,
                          const float* __restrict__ smax,
                          const float* __restrict__ wrv,
                          unsigned* __restrict__ rowcnt,
                          unsigned short* __restrict__ cand)
{
    SCAN_PROLOGUE();
    float thr[4];
    #pragma unroll
    for (int nt = 0; nt < 4; ++nt) {
        int row = rowv[nt];
        float m = -1e30f;
        #pragma unroll
        for (int s = 0; s < NSPLIT; ++s)
            m = fmaxf(m, smax[(size_t)s * N_ROWS + row]);
        thr[nt] = m - wrv[row];
    }

    #pragma unroll 1
    for (int ct = 0; ct < CPS / 16; ++ct) {
        const int code0 = code_base + ct * 16;
        const unsigned short* ap = cbbf + (size_t)(code0 + l15) * DIM + lc * 8;
        bf16x8 a0 = ldbf8(ap), a1 = ldbf8(ap + 32);
        #pragma unroll
        for (int nt = 0; nt < 4; ++nt) {
            f32x4 acc = {0.f, 0.f, 0.f, 0.f};
            acc = __builtin_amdgcn_mfma_f32_16x16x32_bf16(a0, bfrag[nt][0], acc, 0, 0, 0);
            acc = __builtin_amdgcn_mfma_f32_16x16x32_bf16(a1, bfrag[nt][1], acc, 0, 0, 0);
            #pragma unroll
            for (int j = 0; j < 4; ++j) {
                if (acc[j] >= thr[nt]) {
                    int row  = rowv[nt];
                    int code = code0 + lc * 4 + j;        // C: m=(lane>>4)*4+reg
                    unsigned pos = atomicAdd(&rowcnt[row], 1u);
                    if (pos < MAXCAND)
                        cand[(size_t)row * MAXCAND + pos] = (unsigned short)code;
                }
            }
        }
    }
}

// ---- rescore: exact fp32 distance on candidates, (d, idx) tie-break ----
__global__ __launch_bounds__(256)
void vq_rescore_kernel(const float* __restrict__ z, const float* __restrict__ cb,
                       const float* __restrict__ znv,
                       const unsigned* __restrict__ rowcnt,
                       const unsigned short* __restrict__ cand,
                       int* __restrict__ bidx)
{
    const int row = blockIdx.x * 256 + threadIdx.x;
    const float zn = znv[row];
    float4 zr[16];
    #pragma unroll
    for (int q = 0; q < 16; ++q)
        zr[q] = ((const float4*)(z + (size_t)row * DIM))[q];

    float bd = __builtin_inff();
    int   bi = 0;
    const unsigned cnt = rowcnt[row];
    if (cnt <= MAXCAND) {
        for (unsigned c = 0; c < cnt; ++c) {
            int code = cand[(size_t)row * MAXCAND + c];
            const float4* ep = (const float4*)(cb + (size_t)code * DIM);
            float a = 0.0f;
            #pragma unroll
            for (int q = 0; q < 16; ++q) {
                float4 e = ep[q];
                a = fmaf(zr[q].x, e.x, a);
                a = fmaf(zr[q].y, e.y, a);
                a = fmaf(zr[q].z, e.z, a);
                a = fmaf(zr[q].w, e.w, a);
            }
            float d = __fsub_rn(zn, __fmul_rn(2.0f, a));
            if (d < bd || (d == bd && code < bi)) { bd = d; bi = code; }
        }
    } else {
        // overflow fallback: exact scan of the whole codebook (codes ascending)
        for (int code = 0; code < K_CODES; ++code) {
            const float4* ep = (const float4*)(cb + (size_t)code * DIM);
            float a = 0.0f;
            #pragma unroll
            for (int q = 0; q < 16; ++q) {
                float4 e = ep[q];
                a = fmaf(zr[q].x, e.x, a);
                a = fmaf(zr[q].y, e.y, a);
                a = fmaf(zr[q].z, e.z, a);
                a = fmaf(zr[q].w, e.w, a);
            }
            float d = __fsub_rn(zn, __fmul_rn(2.0f, a));
            if (d < bd) { bd = d; bi = code; }
        }
    }
    bidx[row] = bi;
}

// ---- epilogue: gather, STE, loss partials ----
__global__ __launch_bounds__(EPI_THREADS, 1)
void vq_epilogue_kernel(const float* __restrict__ z, const float* __restrict__ cb,
                        const int* __restrict__ bidx,
                        float* __restrict__ out, float* __restrict__ lred)
{
    __shared__ int   sbesti[64];
    __shared__ float sred[EPI_THREADS];

    const int tid  = threadIdx.x;
    const int blk  = blockIdx.x;
    const int row0 = blk * 64;

    if (tid < 64) sbesti[tid] = bidx[row0 + tid];
    __syncthreads();

    float lsum = 0.0f;
    #pragma unroll
    for (int it = 0; it < (64 * DIM / 4) / EPI_THREADS; ++it) {
        int lin = it * EPI_THREADS + tid;
        int r = lin >> 4, dg = lin & 15;
        int idx = sbesti[r];
        float4 q  = *(const float4*)(cb + (size_t)idx * DIM + dg * 4);
        float4 zv = *(const float4*)(z + (size_t)(row0 + r) * DIM + dg * 4);
        float4 o;
        float t;
        t = q.x - zv.x; o.x = zv.x + t; lsum = fmaf(t, t, lsum);
        t = q.y - zv.y; o.y = zv.y + t; lsum = fmaf(t, t, lsum);
        t = q.z - zv.z; o.z = zv.z + t; lsum = fmaf(t, t, lsum);
        t = q.w - zv.w; o.w = zv.w + t; lsum = fmaf(t, t, lsum);
        *(float4*)(out + (size_t)(row0 + r) * DIM + dg * 4) = o;
    }
    if (tid < 64)
        out[(size_t)N_ROWS * DIM + row0 + tid] = (float)sbesti[tid];

    sred[tid] = lsum;
    __syncthreads();
    for (int s = EPI_THREADS / 2; s > 0; s >>= 1) {
        if (tid < s) sred[tid] = sred[tid] + sred[tid + s];
        __syncthreads();
    }
    if (tid == 0) lred[blk] = sred[0];
}

__global__ void vq_loss_kernel(const float* __restrict__ lred, float* __restrict__ out)
{
    __shared__ float sred[EPI_BLOCKS];
    int tid = threadIdx.x;
    sred[tid] = lred[tid];
    __syncthreads();
    for (int s = EPI_BLOCKS / 2; s > 0; s >>= 1) {
        if (tid < s) sred[tid] = sred[tid] + sred[tid + s];
        __syncthreads();
    }
    if (tid == 0) {
        float m = sred[0] / (float)((size_t)N_ROWS * DIM);
        out[(size_t)N_ROWS * DIM + N_ROWS] = __fadd_rn(m, __fmul_rn(0.25f, m));
    }
}

extern "C" void kernel_launch(void* const* d_in, const int* in_sizes, int n_in,
                              void* d_out, int out_size, void* d_ws, size_t ws_size,
                              hipStream_t stream)
{
    const float* z  = (const float*)d_in[0];
    const float* cb = (const float*)d_in[1];
    float* out = (float*)d_out;

    unsigned short* zbf  = WS_ZBF(d_ws);
    unsigned short* cbbf = WS_CBBF(d_ws);
    float*          zn   = WS_ZN(d_ws);
    float*          wr   = WS_WR(d_ws);
    unsigned*       cnt  = WS_CNT(d_ws);
    int*            bidx = WS_BIDX(d_ws);
    float*          lred = WS_LRED(d_ws);
    float*          smax = OUT_SMAX(d_out);
    unsigned short* cand = OUT_CAND(d_out);

    hipLaunchKernelGGL(vq_prep_kernel, dim3(N_ROWS / 256), dim3(256), 0, stream,
                       z, zn, wr, zbf, cnt);
    hipLaunchKernelGGL(vq_cbconv_kernel, dim3(K_CODES / 256), dim3(256), 0, stream,
                       cb, cbbf);
    hipLaunchKernelGGL(vq_scanmax_kernel, dim3(SCAN_BLOCKS), dim3(256), 0, stream,
                       zbf, cbbf, smax);
    hipLaunchKernelGGL(vq_scanfilter_kernel, dim3(SCAN_BLOCKS), dim3(256), 0, stream,
                       zbf, cbbf, smax, wr, cnt, cand);
    hipLaunchKernelGGL(vq_rescore_kernel, dim3(N_ROWS / 256), dim3(256), 0, stream,
                       z, cb, zn, cnt, cand, bidx);
    hipLaunchKernelGGL(vq_epilogue_kernel, dim3(EPI_BLOCKS), dim3(EPI_THREADS), 0, stream,
                       z, cb, bidx, out, lred);
    hipLaunchKernelGGL(vq_loss_kernel, dim3(1), dim3(EPI_BLOCKS), 0, stream,
                       lred, out);
}

// Round 7
// 115.341 us; speedup vs baseline: 23.9359x; 23.9359x over previous
//
#include <hip/hip_runtime.h>

#define N_ROWS   16384
#define DIM      64
#define K_CODES  8192
#define EMAX     (1.0f / 8192.0f)
#define NSPLIT   16
#define CPS      (K_CODES / NSPLIT)          // 512 codes per slice
#define SCAN_BLOCKS 1024                      // 4096 waves: 256 rowgrps x 16 splits
#define EPI_BLOCKS  (N_ROWS / 64)            // 256
#define EPI_THREADS 512
#define MAXCAND  64

typedef __attribute__((ext_vector_type(8))) short bf16x8;
typedef __attribute__((ext_vector_type(4))) float f32x4;

// ---- ws layout ----
// [0, 2MB)      : zbf   ushort[N_ROWS*64]
// [2MB, 3MB)    : cbbf  ushort[K_CODES*64]
// [3MB, +64KB)  : zn    float[N_ROWS]
// +64KB         : wr    float[N_ROWS]
// +128KB        : rowcnt uint[N_ROWS]
// +192KB        : bidx  int[N_ROWS]
// +256KB        : lred  float[EPI_BLOCKS]
#define WS_ZBF(ws)  ((unsigned short*)(ws))
#define WS_CBBF(ws) ((unsigned short*)((char*)(ws) + (2u<<20)))
#define WS_ZN(ws)   ((float*)((char*)(ws) + (3u<<20)))
#define WS_WR(ws)   ((float*)((char*)(ws) + (3u<<20) + (64u<<10)))
#define WS_CNT(ws)  ((unsigned*)((char*)(ws) + (3u<<20) + (128u<<10)))
#define WS_BIDX(ws) ((int*)((char*)(ws) + (3u<<20) + (192u<<10)))
#define WS_LRED(ws) ((float*)((char*)(ws) + (3u<<20) + (256u<<10)))
// scratch hosted in d_out (rewritten every call before use; epilogue then
// overwrites every out element):
//   smax float[NSPLIT][N_ROWS] at out+0 (1MB)
//   cand ushort[N_ROWS][MAXCAND] at out+1MB (2MB) -> spans [1MB,3MB) of 4MB z_q
#define OUT_SMAX(out) ((float*)(out))
#define OUT_CAND(out) ((unsigned short*)((char*)(out) + (1u<<20)))

__device__ __forceinline__ unsigned short f2bf_rn(float x) {
    unsigned u = __float_as_uint(x);
    return (unsigned short)((u + 0x7FFFu + ((u >> 16) & 1u)) >> 16);
}
__device__ __forceinline__ bf16x8 ldbf8(const unsigned short* p) {
    uint4 t = *(const uint4*)p;
    return *(bf16x8*)&t;
}

// ---- prep: zn (exact chain), window, bf16(z), zero counters ----
__global__ __launch_bounds__(256)
void vq_prep_kernel(const float* __restrict__ z, float* __restrict__ zn_o,
                    float* __restrict__ wr_o, unsigned short* __restrict__ zbf,
                    unsigned* __restrict__ rowcnt)
{
    const int row = blockIdx.x * 256 + threadIdx.x;
    float zs[DIM];
    #pragma unroll
    for (int ch = 0; ch < 16; ++ch) {
        float4 v = *(const float4*)(z + (size_t)row * DIM + ch * 4);
        zs[4*ch+0] = v.x; zs[4*ch+1] = v.y; zs[4*ch+2] = v.z; zs[4*ch+3] = v.w;
    }
    float r8[8];
    #pragma unroll
    for (int j = 0; j < 8; ++j) r8[j] = __fmul_rn(zs[j], zs[j]);
    #pragma unroll
    for (int i = 8; i < DIM; i += 8)
        #pragma unroll
        for (int j = 0; j < 8; ++j)
            r8[j] = __fadd_rn(r8[j], __fmul_rn(zs[i+j], zs[i+j]));
    float zn = __fadd_rn(__fadd_rn(__fadd_rn(r8[0], r8[1]), __fadd_rn(r8[2], r8[3])),
                         __fadd_rn(__fadd_rn(r8[4], r8[5]), __fadd_rn(r8[6], r8[7])));
    float S = 0.0f;
    #pragma unroll
    for (int k = 0; k < DIM; ++k) S += fabsf(zs[k]);

    zn_o[row] = zn;
    wr_o[row] = 0x1p-6f * EMAX * S * 1.02f + 2e-5f;
    rowcnt[row] = 0u;

    #pragma unroll
    for (int g = 0; g < 8; ++g) {
        uint4 o;
        o.x = (unsigned)f2bf_rn(zs[8*g+0]) | ((unsigned)f2bf_rn(zs[8*g+1]) << 16);
        o.y = (unsigned)f2bf_rn(zs[8*g+2]) | ((unsigned)f2bf_rn(zs[8*g+3]) << 16);
        o.z = (unsigned)f2bf_rn(zs[8*g+4]) | ((unsigned)f2bf_rn(zs[8*g+5]) << 16);
        o.w = (unsigned)f2bf_rn(zs[8*g+6]) | ((unsigned)f2bf_rn(zs[8*g+7]) << 16);
        *(uint4*)(zbf + (size_t)row * DIM + g * 8) = o;
    }
}

__global__ __launch_bounds__(256)
void vq_cbconv_kernel(const float* __restrict__ cb, unsigned short* __restrict__ cbbf)
{
    const int code = blockIdx.x * 256 + threadIdx.x;
    #pragma unroll
    for (int g = 0; g < 8; ++g) {
        float4 a = *(const float4*)(cb + (size_t)code * DIM + g * 8);
        float4 b = *(const float4*)(cb + (size_t)code * DIM + g * 8 + 4);
        uint4 o;
        o.x = (unsigned)f2bf_rn(a.x) | ((unsigned)f2bf_rn(a.y) << 16);
        o.y = (unsigned)f2bf_rn(a.z) | ((unsigned)f2bf_rn(a.w) << 16);
        o.z = (unsigned)f2bf_rn(b.x) | ((unsigned)f2bf_rn(b.y) << 16);
        o.w = (unsigned)f2bf_rn(b.z) | ((unsigned)f2bf_rn(b.w) << 16);
        *(uint4*)(cbbf + (size_t)code * DIM + g * 8) = o;
    }
}

// ---- common wave setup for scans: B frags (z rows) in regs ----
#define SCAN_PROLOGUE()                                                        \
    const int lane = threadIdx.x & 63;                                         \
    const int gw   = blockIdx.x * 4 + (threadIdx.x >> 6);                      \
    const int rowgrp = gw >> 4;                                                \
    const int split  = gw & (NSPLIT - 1);                                      \
    const int code_base = split * CPS;                                         \
    const int l15 = lane & 15, lc = lane >> 4;                                 \
    bf16x8 bfrag[4][2];                                                        \
    int rowv[4];                                                               \
    _Pragma("unroll")                                                          \
    for (int nt = 0; nt < 4; ++nt) {                                           \
        int row = rowgrp * 64 + nt * 16 + l15;                                 \
        rowv[nt] = row;                                                        \
        const unsigned short* p = zbf + (size_t)row * DIM + lc * 8;            \
        bfrag[nt][0] = ldbf8(p);                                               \
        bfrag[nt][1] = ldbf8(p + 32);                                          \
    }                                                                          \
    _Pragma("unroll")                                                          \
    for (int nt = 0; nt < 4; ++nt) {                                           \
        uint4& u0 = *(uint4*)&bfrag[nt][0];                                    \
        asm volatile("" : "+v"(u0.x), "+v"(u0.y), "+v"(u0.z), "+v"(u0.w));     \
        uint4& u1 = *(uint4*)&bfrag[nt][1];                                    \
        asm volatile("" : "+v"(u1.x), "+v"(u1.y), "+v"(u1.z), "+v"(u1.w));     \
    }

// ---- scan A: per-(row, slice) max of bf16 dot ----
__global__ __launch_bounds__(256, 4)
void vq_scanmax_kernel(const unsigned short* __restrict__ zbf,
                       const unsigned short* __restrict__ cbbf,
                       float* __restrict__ smax)
{
    SCAN_PROLOGUE();
    float vmax[4];
    #pragma unroll
    for (int nt = 0; nt < 4; ++nt) vmax[nt] = -1e30f;

    #pragma unroll 1
    for (int ct = 0; ct < CPS / 16; ++ct) {
        const unsigned short* ap = cbbf + (size_t)(code_base + ct * 16 + l15) * DIM + lc * 8;
        bf16x8 a0 = ldbf8(ap), a1 = ldbf8(ap + 32);
        #pragma unroll
        for (int nt = 0; nt < 4; ++nt) {
            f32x4 acc = {0.f, 0.f, 0.f, 0.f};
            acc = __builtin_amdgcn_mfma_f32_16x16x32_bf16(a0, bfrag[nt][0], acc, 0, 0, 0);
            acc = __builtin_amdgcn_mfma_f32_16x16x32_bf16(a1, bfrag[nt][1], acc, 0, 0, 0);
            vmax[nt] = fmaxf(vmax[nt],
                             fmaxf(fmaxf(acc[0], acc[1]), fmaxf(acc[2], acc[3])));
        }
    }
    #pragma unroll
    for (int nt = 0; nt < 4; ++nt) {
        float v = vmax[nt];
        v = fmaxf(v, __shfl_xor(v, 16));
        v = fmaxf(v, __shfl_xor(v, 32));
        if (lc == 0) smax[(size_t)split * N_ROWS + rowv[nt]] = v;
    }
}

// ---- scan B: filter vs global-row threshold, append candidate codes ----
__global__ __launch_bounds__(256, 4)
void vq_scanfilter_kernel(const unsigned short* __restrict__ zbf,
                          const unsigned short* __restrict__ cbbf,
                          const float* __restrict__ smax,
                          const float* __restrict__ wrv,
                          unsigned* __restrict__ rowcnt,
                          unsigned short* __restrict__ cand)
{
    SCAN_PROLOGUE();
    float thr[4];
    #pragma unroll
    for (int nt = 0; nt < 4; ++nt) {
        int row = rowv[nt];
        float m = -1e30f;
        #pragma unroll
        for (int s = 0; s < NSPLIT; ++s)
            m = fmaxf(m, smax[(size_t)s * N_ROWS + row]);
        thr[nt] = m - wrv[row];
    }

    #pragma unroll 1
    for (int ct = 0; ct < CPS / 16; ++ct) {
        const int code0 = code_base + ct * 16;
        const unsigned short* ap = cbbf + (size_t)(code0 + l15) * DIM + lc * 8;
        bf16x8 a0 = ldbf8(ap), a1 = ldbf8(ap + 32);
        #pragma unroll
        for (int nt = 0; nt < 4; ++nt) {
            f32x4 acc = {0.f, 0.f, 0.f, 0.f};
            acc = __builtin_amdgcn_mfma_f32_16x16x32_bf16(a0, bfrag[nt][0], acc, 0, 0, 0);
            acc = __builtin_amdgcn_mfma_f32_16x16x32_bf16(a1, bfrag[nt][1], acc, 0, 0, 0);
            #pragma unroll
            for (int j = 0; j < 4; ++j) {
                if (acc[j] >= thr[nt]) {
                    int row  = rowv[nt];
                    int code = code0 + lc * 4 + j;        // C: m=(lane>>4)*4+reg
                    unsigned pos = atomicAdd(&rowcnt[row], 1u);
                    if (pos < MAXCAND)
                        cand[(size_t)row * MAXCAND + pos] = (unsigned short)code;
                }
            }
        }
    }
}

// ---- rescore: ONE WAVE PER ROW; lane-parallel candidates; wave-parallel
//      full-scan fallback. (d, idx) reduce == reference tie-break, and is
//      order-independent => deterministic despite atomic append order. ----
__global__ __launch_bounds__(256)
void vq_rescore_kernel(const float* __restrict__ z, const float* __restrict__ cb,
                       const float* __restrict__ znv,
                       const unsigned* __restrict__ rowcnt,
                       const unsigned short* __restrict__ cand,
                       int* __restrict__ bidx)
{
    const int lane = threadIdx.x & 63;
    const int row  = blockIdx.x * 4 + (threadIdx.x >> 6);
    const float zn = znv[row];
    const unsigned cnt = rowcnt[row];
    const float4* zp = (const float4*)(z + (size_t)row * DIM);

    float bd = __builtin_inff();
    int   bi = 0x7fffffff;

    if (cnt <= MAXCAND) {
        if (lane < (int)cnt) {
            int code = cand[(size_t)row * MAXCAND + lane];
            const float4* ep = (const float4*)(cb + (size_t)code * DIM);
            float a = 0.0f;
            #pragma unroll
            for (int q = 0; q < 16; ++q) {
                float4 zv = zp[q], e = ep[q];
                a = fmaf(zv.x, e.x, a);
                a = fmaf(zv.y, e.y, a);
                a = fmaf(zv.z, e.z, a);
                a = fmaf(zv.w, e.w, a);
            }
            bd = __fsub_rn(zn, __fmul_rn(2.0f, a));
            bi = code;
        }
    } else {
        // wave-parallel exact scan: lane handles codes lane, lane+64, ...
        float4 zr[16];
        #pragma unroll
        for (int q = 0; q < 16; ++q) zr[q] = zp[q];
        for (int code = lane; code < K_CODES; code += 64) {
            const float4* ep = (const float4*)(cb + (size_t)code * DIM);
            float a = 0.0f;
            #pragma unroll
            for (int q = 0; q < 16; ++q) {
                float4 e = ep[q];
                a = fmaf(zr[q].x, e.x, a);
                a = fmaf(zr[q].y, e.y, a);
                a = fmaf(zr[q].z, e.z, a);
                a = fmaf(zr[q].w, e.w, a);
            }
            float d = __fsub_rn(zn, __fmul_rn(2.0f, a));
            if (d < bd) { bd = d; bi = code; }   // ascending per lane
        }
    }

    #pragma unroll
    for (int m = 32; m >= 1; m >>= 1) {
        float od = __shfl_xor(bd, m);
        int   oi = __shfl_xor(bi, m);
        if (od < bd || (od == bd && oi < bi)) { bd = od; bi = oi; }
    }
    if (lane == 0) bidx[row] = bi;
}

// ---- epilogue: gather, STE, loss partials ----
__global__ __launch_bounds__(EPI_THREADS, 1)
void vq_epilogue_kernel(const float* __restrict__ z, const float* __restrict__ cb,
                        const int* __restrict__ bidx,
                        float* __restrict__ out, float* __restrict__ lred)
{
    __shared__ int   sbesti[64];
    __shared__ float sred[EPI_THREADS];

    const int tid  = threadIdx.x;
    const int blk  = blockIdx.x;
    const int row0 = blk * 64;

    if (tid < 64) sbesti[tid] = bidx[row0 + tid];
    __syncthreads();

    float lsum = 0.0f;
    #pragma unroll
    for (int it = 0; it < (64 * DIM / 4) / EPI_THREADS; ++it) {
        int lin = it * EPI_THREADS + tid;
        int r = lin >> 4, dg = lin & 15;
        int idx = sbesti[r];
        float4 q  = *(const float4*)(cb + (size_t)idx * DIM + dg * 4);
        float4 zv = *(const float4*)(z + (size_t)(row0 + r) * DIM + dg * 4);
        float4 o;
        float t;
        t = q.x - zv.x; o.x = zv.x + t; lsum = fmaf(t, t, lsum);
        t = q.y - zv.y; o.y = zv.y + t; lsum = fmaf(t, t, lsum);
        t = q.z - zv.z; o.z = zv.z + t; lsum = fmaf(t, t, lsum);
        t = q.w - zv.w; o.w = zv.w + t; lsum = fmaf(t, t, lsum);
        *(float4*)(out + (size_t)(row0 + r) * DIM + dg * 4) = o;
    }
    if (tid < 64)
        out[(size_t)N_ROWS * DIM + row0 + tid] = (float)sbesti[tid];

    sred[tid] = lsum;
    __syncthreads();
    for (int s = EPI_THREADS / 2; s > 0; s >>= 1) {
        if (tid < s) sred[tid] = sred[tid] + sred[tid + s];
        __syncthreads();
    }
    if (tid == 0) lred[blk] = sred[0];
}

__global__ void vq_loss_kernel(const float* __restrict__ lred, float* __restrict__ out)
{
    __shared__ float sred[EPI_BLOCKS];
    int tid = threadIdx.x;
    sred[tid] = lred[tid];
    __syncthreads();
    for (int s = EPI_BLOCKS / 2; s > 0; s >>= 1) {
        if (tid < s) sred[tid] = sred[tid] + sred[tid + s];
        __syncthreads();
    }
    if (tid == 0) {
        float m = sred[0] / (float)((size_t)N_ROWS * DIM);
        out[(size_t)N_ROWS * DIM + N_ROWS] = __fadd_rn(m, __fmul_rn(0.25f, m));
    }
}

extern "C" void kernel_launch(void* const* d_in, const int* in_sizes, int n_in,
                              void* d_out, int out_size, void* d_ws, size_t ws_size,
                              hipStream_t stream)
{
    const float* z  = (const float*)d_in[0];
    const float* cb = (const float*)d_in[1];
    float* out = (float*)d_out;

    unsigned short* zbf  = WS_ZBF(d_ws);
    unsigned short* cbbf = WS_CBBF(d_ws);
    float*          zn   = WS_ZN(d_ws);
    float*          wr   = WS_WR(d_ws);
    unsigned*       cnt  = WS_CNT(d_ws);
    int*            bidx = WS_BIDX(d_ws);
    float*          lred = WS_LRED(d_ws);
    float*          smax = OUT_SMAX(d_out);
    unsigned short* cand = OUT_CAND(d_out);

    hipLaunchKernelGGL(vq_prep_kernel, dim3(N_ROWS / 256), dim3(256), 0, stream,
                       z, zn, wr, zbf, cnt);
    hipLaunchKernelGGL(vq_cbconv_kernel, dim3(K_CODES / 256), dim3(256), 0, stream,
                       cb, cbbf);
    hipLaunchKernelGGL(vq_scanmax_kernel, dim3(SCAN_BLOCKS), dim3(256), 0, stream,
                       zbf, cbbf, smax);
    hipLaunchKernelGGL(vq_scanfilter_kernel, dim3(SCAN_BLOCKS), dim3(256), 0, stream,
                       zbf, cbbf, smax, wr, cnt, cand);
    hipLaunchKernelGGL(vq_rescore_kernel, dim3(N_ROWS / 4), dim3(256), 0, stream,
                       z, cb, zn, cnt, cand, bidx);
    hipLaunchKernelGGL(vq_epilogue_kernel, dim3(EPI_BLOCKS), dim3(EPI_THREADS), 0, stream,
                       z, cb, bidx, out, lred);
    hipLaunchKernelGGL(vq_loss_kernel, dim3(1), dim3(EPI_BLOCKS), 0, stream,
                       lred, out);
}